// Round 2
// baseline (246.951 us; speedup 1.0000x reference)
//
#include <hip/hip_runtime.h>
#include <cstdint>
#include <cstddef>

#define BB 16
#define NN 4096
#define CC 80
#define MAXD 100
#define IOU_T 0.5f
#define CONF_T 0.5f
#define RSTRIDE 81   // 80 + 1 pad: kills 32-way LDS bank conflict on row access

// ---------------------------------------------------------------------------
// K1: softmax of (10x)^2 per row, one THREAD per row, 64 rows per block.
// Replicates numpy's pairwise_sum DAG for n=80 exactly (8 accumulators,
// stride-8 interleave, ((r0+r1)+(r2+r3))+((r4+r5)+(r6+r7))) so that the
// "score == 1.0f" tie-group membership matches the np reference bitwise.
// fp contract OFF: fl(y*y)-m must be two roundings, as in numpy.
// ---------------------------------------------------------------------------
__global__ __launch_bounds__(64) void k_softmax(const float* __restrict__ cls_in,
                                                float* __restrict__ probs,
                                                uint64_t* __restrict__ keys) {
#pragma clang fp contract(off)
    __shared__ float buf[64 * RSTRIDE];
    int t = threadIdx.x;
    size_t gbase = (size_t)blockIdx.x * 64 * CC;

    for (int i = t; i < 64 * CC; i += 64) {
        int r = i / CC, c = i - r * CC;
        buf[r * RSTRIDE + c] = cls_in[gbase + i];
    }
    __syncthreads();

    float* row = buf + t * RSTRIDE;

    // pass 1: z = (x*10)^2, row max (order-independent)
    float m = -3.402823466e+38f;
    for (int c = 0; c < CC; ++c) {
        float y = row[c] * 10.0f;
        float z = y * y;
        m = fmaxf(m, z);
    }
    // pass 2: e = exp(z - m), overwrite row
    for (int c = 0; c < CC; ++c) {
        float y = row[c] * 10.0f;
        float z = y * y;
        row[c] = expf(z - m);
    }
    // pass 3: numpy pairwise-8 summation DAG (n=80, no remainder)
    float r8[8];
    #pragma unroll
    for (int j = 0; j < 8; ++j) r8[j] = row[j];
    for (int i = 8; i < CC; i += 8) {
        #pragma unroll
        for (int j = 0; j < 8; ++j) r8[j] += row[i + j];
    }
    float s = ((r8[0] + r8[1]) + (r8[2] + r8[3])) + ((r8[4] + r8[5]) + (r8[6] + r8[7]));

    // probs = e / s (elementwise, matches np division bitwise given same e,s)
    for (int c = 0; c < CC; ++c) row[c] = row[c] / s;

    // composite sort key: (score desc, idx asc) == stable descending sort
    int gw = blockIdx.x * 64 + t;
    float score = 1.0f / s;                 // max softmax element = fl(1/s)
    unsigned n = (unsigned)(gw & (NN - 1));
    keys[gw] = ((uint64_t)__float_as_uint(score) << 32)
             | (uint64_t)(0xFFFFFFFFu - n);

    __syncthreads();
    for (int i = t; i < 64 * CC; i += 64) {
        int r = i / CC, c = i - r * CC;
        probs[gbase + i] = buf[r * RSTRIDE + c];
    }
}

// ---------------------------------------------------------------------------
// K2: per-batch bitonic sort (descending) of 4096 uint64 keys in LDS.
// ---------------------------------------------------------------------------
__global__ __launch_bounds__(1024) void k_sort(uint64_t* __restrict__ keys) {
    __shared__ uint64_t sk[NN];
    uint64_t* kb = keys + (size_t)blockIdx.x * NN;
    for (int i = threadIdx.x; i < NN; i += 1024) sk[i] = kb[i];
    __syncthreads();

    for (unsigned k = 2; k <= NN; k <<= 1) {
        for (unsigned j = k >> 1; j > 0; j >>= 1) {
            for (unsigned i = threadIdx.x; i < NN; i += 1024) {
                unsigned p = i ^ j;
                if (p > i) {
                    uint64_t a = sk[i], b = sk[p];
                    bool desc = ((i & k) == 0);
                    if (desc ? (a < b) : (a > b)) { sk[i] = b; sk[p] = a; }
                }
            }
            __syncthreads();
        }
    }
    for (int i = threadIdx.x; i < NN; i += 1024) kb[i] = sk[i];
}

// ---------------------------------------------------------------------------
// K3: greedy NMS per batch, one wave per batch, 64-candidate chunks,
// early exit at 100 kept. All IOU math is IEEE-exact ops, contract OFF so
// it is bitwise identical to the np reference's comparisons.
// ---------------------------------------------------------------------------
__global__ __launch_bounds__(64) void k_nms(const uint64_t* __restrict__ keys,
                                            const float* __restrict__ boxes,
                                            const float* __restrict__ probs,
                                            float* __restrict__ out_box,
                                            float* __restrict__ out_cls) {
#pragma clang fp contract(off)
    int b    = blockIdx.x;
    int lane = threadIdx.x;

    __shared__ float ky1[MAXD], kx1[MAXD], ky2[MAXD], kx2[MAXD], kar[MAXD];
    __shared__ int   kidx[MAXD];
    __shared__ float cy1[64], cx1[64], cy2[64], cx2[64], car[64];
    __shared__ uint64_t kill[64];

    const uint64_t* kb = keys + (size_t)b * NN;
    const float* bx = boxes + (size_t)b * NN * 4;

    int kept = 0;
    for (int base = 0; base < NN && kept < MAXD; base += 64) {
        uint64_t key = kb[base + lane];
        float score = __uint_as_float((unsigned)(key >> 32));
        int idx = (int)(0xFFFFFFFFu - (unsigned)(key & 0xFFFFFFFFull));
        bool valid = score > CONF_T;

        float b0 = bx[idx * 4 + 0], b1 = bx[idx * 4 + 1];
        float b2 = bx[idx * 4 + 2], b3 = bx[idx * 4 + 3];
        float y1 = fminf(b0, b2), y2 = fmaxf(b0, b2);
        float x1 = fminf(b1, b3), x2 = fmaxf(b1, b3);
        float ar = (y2 - y1) * (x2 - x1);

        cy1[lane] = y1; cx1[lane] = x1; cy2[lane] = y2; cx2[lane] = x2;
        car[lane] = ar;
        __syncthreads();

        // suppression by already-kept boxes (previous chunks)
        bool sup = false;
        for (int k2 = 0; k2 < kept; ++k2) {
            float ih = fmaxf(0.0f, fminf(y2, ky2[k2]) - fmaxf(y1, ky1[k2]));
            float iw = fmaxf(0.0f, fminf(x2, kx2[k2]) - fmaxf(x1, kx1[k2]));
            float inter = ih * iw;
            float uni = (ar + kar[k2]) - inter;
            float iou = (inter > 0.0f) ? inter / uni : 0.0f;
            sup = sup || (iou > IOU_T);
        }

        // intra-chunk kill mask
        uint64_t km = 0;
        for (int m2 = 0; m2 < 64; ++m2) {
            float ih = fmaxf(0.0f, fminf(y2, cy2[m2]) - fmaxf(y1, cy1[m2]));
            float iw = fmaxf(0.0f, fminf(x2, cx2[m2]) - fmaxf(x1, cx1[m2]));
            float inter = ih * iw;
            float uni = (ar + car[m2]) - inter;
            float iou = (inter > 0.0f) ? inter / uni : 0.0f;
            if (iou > IOU_T) km |= (1ull << m2);
        }
        kill[lane] = km;
        uint64_t elig = __ballot(valid && !sup);
        __syncthreads();

        // sequential greedy scan over chunk slots (uniform across lanes)
        uint64_t suppressed = 0, keptmask = 0;
        for (int j2 = 0; j2 < 64; ++j2) {
            if ((elig >> j2) & 1ull) {
                if (!((suppressed >> j2) & 1ull)) {
                    keptmask  |= 1ull << j2;
                    suppressed |= kill[j2];
                }
            }
        }

        if ((keptmask >> lane) & 1ull) {
            int slot = kept + __popcll(keptmask & ((1ull << lane) - 1ull));
            if (slot < MAXD) {
                ky1[slot] = y1; kx1[slot] = x1; ky2[slot] = y2; kx2[slot] = x2;
                kar[slot] = ar; kidx[slot] = idx;
            }
        }
        kept += __popcll(keptmask);
        __syncthreads();
    }

    int count = kept < MAXD ? kept : MAXD;
    __syncthreads();

    float* ob = out_box + (size_t)b * MAXD * 4;
    for (int u = lane; u < MAXD * 4; u += 64) {
        int t = u >> 2, e = u & 3;
        ob[u] = (t < count) ? bx[kidx[t] * 4 + e] : 0.0f;
    }
    const float* pr = probs + (size_t)b * NN * CC;
    float* oc = out_cls + (size_t)b * MAXD * CC;
    for (int u = lane; u < MAXD * CC; u += 64) {
        int t = u / CC, c2 = u % CC;
        oc[u] = (t < count) ? pr[kidx[t] * CC + c2] : 0.0f;
    }
}

extern "C" void kernel_launch(void* const* d_in, const int* in_sizes, int n_in,
                              void* d_out, int out_size, void* d_ws, size_t ws_size,
                              hipStream_t stream) {
    const float* boxes = (const float*)d_in[0];   // [B,N,4]
    const float* cls   = (const float*)d_in[1];   // [B,N,C]
    float* out = (float*)d_out;
    float* out_box = out;                                                  // [B,100,4]
    float* out_cls = out + (size_t)BB * MAXD * 4;                          // [B,100,80]
    float* probs   = out + (size_t)BB * MAXD * 4 + (size_t)BB * MAXD * CC; // [B,N,80]
    uint64_t* keys = (uint64_t*)d_ws;                                      // [B,N]

    k_softmax<<<(BB * NN) / 64, 64, 0, stream>>>(cls, probs, keys);
    k_sort<<<BB, 1024, 0, stream>>>(keys);
    k_nms<<<BB, 64, 0, stream>>>(keys, boxes, probs, out_box, out_cls);
}

// Round 3
// 213.632 us; speedup vs baseline: 1.1560x; 1.1560x over previous
//
#include <hip/hip_runtime.h>
#include <cstdint>
#include <cstddef>

#define BB 16
#define NN 4096
#define CC 80
#define MAXD 100
#define IOU_T 0.5f
#define CONF_T 0.5f
#define RSTRIDE 81   // 80 + 1 pad: kills 32-way LDS bank conflict on row access
#define PER_B (MAXD * 4 + MAXD * CC)   // 8400 output elems per batch

// ---------------------------------------------------------------------------
// K1: softmax of (10x)^2 per row, one THREAD per row, 64 rows per block.
// Replicates numpy's pairwise_sum DAG for n=80 exactly (8 accumulators,
// stride-8 interleave, ((r0+r1)+(r2+r3))+((r4+r5)+(r6+r7))) so that the
// "score == 1.0f" tie-group membership matches the np reference bitwise.
// fp contract OFF: fl(y*y)-m must be two roundings, as in numpy.
// ---------------------------------------------------------------------------
__global__ __launch_bounds__(64) void k_softmax(const float* __restrict__ cls_in,
                                                float* __restrict__ probs,
                                                uint64_t* __restrict__ keys) {
#pragma clang fp contract(off)
    __shared__ float buf[64 * RSTRIDE];
    int t = threadIdx.x;
    size_t gbase = (size_t)blockIdx.x * 64 * CC;

    for (int i = t; i < 64 * CC; i += 64) {
        int r = i / CC, c = i - r * CC;
        buf[r * RSTRIDE + c] = cls_in[gbase + i];
    }
    __syncthreads();

    float* row = buf + t * RSTRIDE;

    // pass 1: z = (x*10)^2, row max (order-independent)
    float m = -3.402823466e+38f;
    for (int c = 0; c < CC; ++c) {
        float y = row[c] * 10.0f;
        float z = y * y;
        m = fmaxf(m, z);
    }
    // pass 2: e = exp(z - m), overwrite row
    for (int c = 0; c < CC; ++c) {
        float y = row[c] * 10.0f;
        float z = y * y;
        row[c] = expf(z - m);
    }
    // pass 3: numpy pairwise-8 summation DAG (n=80, no remainder)
    float r8[8];
    #pragma unroll
    for (int j = 0; j < 8; ++j) r8[j] = row[j];
    for (int i = 8; i < CC; i += 8) {
        #pragma unroll
        for (int j = 0; j < 8; ++j) r8[j] += row[i + j];
    }
    float s = ((r8[0] + r8[1]) + (r8[2] + r8[3])) + ((r8[4] + r8[5]) + (r8[6] + r8[7]));

    // probs = e / s
    for (int c = 0; c < CC; ++c) row[c] = row[c] / s;

    // composite sort key: (score desc, idx asc) == stable descending sort
    int gw = blockIdx.x * 64 + t;
    float score = 1.0f / s;                 // max softmax element = fl(1/s)
    unsigned n = (unsigned)(gw & (NN - 1));
    keys[gw] = ((uint64_t)__float_as_uint(score) << 32)
             | (uint64_t)(0xFFFFFFFFu - n);

    __syncthreads();
    for (int i = t; i < 64 * CC; i += 64) {
        int r = i / CC, c = i - r * CC;
        probs[gbase + i] = buf[r * RSTRIDE + c];
    }
}

// ---------------------------------------------------------------------------
// K2: per-batch bitonic sort (descending) of 4096 uint64 keys in LDS.
// ---------------------------------------------------------------------------
__global__ __launch_bounds__(1024) void k_sort(uint64_t* __restrict__ keys) {
    __shared__ uint64_t sk[NN];
    uint64_t* kb = keys + (size_t)blockIdx.x * NN;
    for (int i = threadIdx.x; i < NN; i += 1024) sk[i] = kb[i];
    __syncthreads();

    for (unsigned k = 2; k <= NN; k <<= 1) {
        for (unsigned j = k >> 1; j > 0; j >>= 1) {
            for (unsigned i = threadIdx.x; i < NN; i += 1024) {
                unsigned p = i ^ j;
                if (p > i) {
                    uint64_t a = sk[i], b = sk[p];
                    bool desc = ((i & k) == 0);
                    if (desc ? (a < b) : (a > b)) { sk[i] = b; sk[p] = a; }
                }
            }
            __syncthreads();
        }
    }
    for (int i = threadIdx.x; i < NN; i += 1024) kb[i] = sk[i];
}

// ---------------------------------------------------------------------------
// K3: greedy NMS core, one wave per batch. Produces ONLY the kept index
// list + count into workspace (the wide gather is a separate parallel
// kernel). Early exit at 100 kept. IEEE-exact IOU math, contract OFF.
// ---------------------------------------------------------------------------
__global__ __launch_bounds__(64) void k_nms(const uint64_t* __restrict__ keys,
                                            const float* __restrict__ boxes,
                                            int* __restrict__ kidx_out,
                                            int* __restrict__ cnt_out) {
#pragma clang fp contract(off)
    int b    = blockIdx.x;
    int lane = threadIdx.x;

    __shared__ float ky1[MAXD], kx1[MAXD], ky2[MAXD], kx2[MAXD], kar[MAXD];
    __shared__ int   kidx[MAXD];
    __shared__ float cy1[64], cx1[64], cy2[64], cx2[64], car[64];
    __shared__ uint64_t kill[64];

    const uint64_t* kb = keys + (size_t)b * NN;
    const float* bx = boxes + (size_t)b * NN * 4;

    int kept = 0;
    for (int base = 0; base < NN && kept < MAXD; base += 64) {
        uint64_t key = kb[base + lane];
        float score = __uint_as_float((unsigned)(key >> 32));
        int idx = (int)(0xFFFFFFFFu - (unsigned)(key & 0xFFFFFFFFull));
        bool valid = score > CONF_T;

        float b0 = bx[idx * 4 + 0], b1 = bx[idx * 4 + 1];
        float b2 = bx[idx * 4 + 2], b3 = bx[idx * 4 + 3];
        float y1 = fminf(b0, b2), y2 = fmaxf(b0, b2);
        float x1 = fminf(b1, b3), x2 = fmaxf(b1, b3);
        float ar = (y2 - y1) * (x2 - x1);

        cy1[lane] = y1; cx1[lane] = x1; cy2[lane] = y2; cx2[lane] = x2;
        car[lane] = ar;
        __syncthreads();

        // suppression by already-kept boxes (previous chunks)
        bool sup = false;
        for (int k2 = 0; k2 < kept; ++k2) {
            float ih = fmaxf(0.0f, fminf(y2, ky2[k2]) - fmaxf(y1, ky1[k2]));
            float iw = fmaxf(0.0f, fminf(x2, kx2[k2]) - fmaxf(x1, kx1[k2]));
            float inter = ih * iw;
            float uni = (ar + kar[k2]) - inter;
            float iou = (inter > 0.0f) ? inter / uni : 0.0f;
            sup = sup || (iou > IOU_T);
        }

        // intra-chunk kill mask
        uint64_t km = 0;
        for (int m2 = 0; m2 < 64; ++m2) {
            float ih = fmaxf(0.0f, fminf(y2, cy2[m2]) - fmaxf(y1, cy1[m2]));
            float iw = fmaxf(0.0f, fminf(x2, cx2[m2]) - fmaxf(x1, cx1[m2]));
            float inter = ih * iw;
            float uni = (ar + car[m2]) - inter;
            float iou = (inter > 0.0f) ? inter / uni : 0.0f;
            if (iou > IOU_T) km |= (1ull << m2);
        }
        kill[lane] = km;
        uint64_t elig = __ballot(valid && !sup);
        __syncthreads();

        // sequential greedy scan over chunk slots (uniform across lanes)
        uint64_t suppressed = 0, keptmask = 0;
        for (int j2 = 0; j2 < 64; ++j2) {
            if ((elig >> j2) & 1ull) {
                if (!((suppressed >> j2) & 1ull)) {
                    keptmask  |= 1ull << j2;
                    suppressed |= kill[j2];
                }
            }
        }

        if ((keptmask >> lane) & 1ull) {
            int slot = kept + __popcll(keptmask & ((1ull << lane) - 1ull));
            if (slot < MAXD) {
                ky1[slot] = y1; kx1[slot] = x1; ky2[slot] = y2; kx2[slot] = x2;
                kar[slot] = ar; kidx[slot] = idx;
            }
        }
        kept += __popcll(keptmask);
        __syncthreads();
    }

    int count = kept < MAXD ? kept : MAXD;
    __syncthreads();

    if (lane == 0) cnt_out[b] = count;
    for (int t = lane; t < MAXD; t += 64)
        kidx_out[b * MAXD + t] = (t < count) ? kidx[t] : 0;
}

// ---------------------------------------------------------------------------
// K4: wide parallel gather. One thread per output element (B*8400 total).
// Coalesced writes; predicated 2-hop loads (kidx -> data).
// ---------------------------------------------------------------------------
__global__ __launch_bounds__(256) void k_gather(const float* __restrict__ boxes,
                                                const float* __restrict__ probs,
                                                const int* __restrict__ kidx,
                                                const int* __restrict__ cnt,
                                                float* __restrict__ out_box,
                                                float* __restrict__ out_cls) {
    int u = blockIdx.x * 256 + threadIdx.x;
    if (u >= BB * PER_B) return;
    int b = u / PER_B;
    int r = u - b * PER_B;
    int count = cnt[b];
    float val = 0.0f;
    if (r < MAXD * 4) {
        int t = r >> 2, e = r & 3;
        if (t < count) {
            int idx = kidx[b * MAXD + t];
            val = boxes[((size_t)b * NN + idx) * 4 + e];
        }
        out_box[(size_t)b * MAXD * 4 + r] = val;
    } else {
        int q = r - MAXD * 4;
        int t = q / CC, c = q - t * CC;
        if (t < count) {
            int idx = kidx[b * MAXD + t];
            val = probs[((size_t)b * NN + idx) * CC + c];
        }
        out_cls[(size_t)b * MAXD * CC + q] = val;
    }
}

extern "C" void kernel_launch(void* const* d_in, const int* in_sizes, int n_in,
                              void* d_out, int out_size, void* d_ws, size_t ws_size,
                              hipStream_t stream) {
    const float* boxes = (const float*)d_in[0];   // [B,N,4]
    const float* cls   = (const float*)d_in[1];   // [B,N,C]
    float* out = (float*)d_out;
    float* out_box = out;                                                  // [B,100,4]
    float* out_cls = out + (size_t)BB * MAXD * 4;                          // [B,100,80]
    float* probs   = out + (size_t)BB * MAXD * 4 + (size_t)BB * MAXD * CC; // [B,N,80]

    uint64_t* keys = (uint64_t*)d_ws;                                      // [B,N]
    int* kidx = (int*)((char*)d_ws + (size_t)BB * NN * sizeof(uint64_t));  // [B,100]
    int* cnt  = kidx + BB * MAXD;                                          // [B]

    k_softmax<<<(BB * NN) / 64, 64, 0, stream>>>(cls, probs, keys);
    k_sort<<<BB, 1024, 0, stream>>>(keys);
    k_nms<<<BB, 64, 0, stream>>>(keys, boxes, kidx, cnt);
    k_gather<<<(BB * PER_B + 255) / 256, 256, 0, stream>>>(boxes, probs, kidx, cnt,
                                                           out_box, out_cls);
}